// Round 2
// baseline (530.344 us; speedup 1.0000x reference)
//
#include <hip/hip_runtime.h>
#include <math.h>

#define NTt 128
#define NSs 128
#define BB  8
#define DD  512
#define VV  32000

#define BM 128
#define BN 128
#define BK 8

// bf16 helpers (manual RNE; inputs are normal floats, no NaN handling needed)
typedef unsigned short ushortT;
typedef unsigned int uintT;
__device__ __forceinline__ ushortT f2bf(float x) {
    uintT u = __float_as_uint(x);
    u = (u + 0x7fffu + ((u >> 16) & 1u)) >> 16;
    return (ushortT)u;
}
__device__ __forceinline__ float bf2f(ushortT h) {
    return __uint_as_float(((uintT)h) << 16);
}

typedef __attribute__((ext_vector_type(8))) short bf16x8;
typedef __attribute__((ext_vector_type(4))) float f32x4;

// ---------------- wfc = Wf @ Wc (D-vector), c0 = NT*(bf.Wc)+bc ----------------
__global__ __launch_bounds__(512)
void wfc_kernel(const float* __restrict__ Wf, const float* __restrict__ Wc,
                const float* __restrict__ bf, const float* __restrict__ bc,
                float* __restrict__ wfc, float* __restrict__ c0) {
    __shared__ float sWc[DD];
    __shared__ float sred[DD];
    const int tid = threadIdx.x;
    sWc[tid] = Wc[tid];
    __syncthreads();
    const float* row = Wf + tid * DD;
    float s = 0.f;
    for (int j = 0; j < DD; j += 4) {
        float4 w = *(const float4*)(row + j);
        s += w.x * sWc[j] + w.y * sWc[j + 1] + w.z * sWc[j + 2] + w.w * sWc[j + 3];
    }
    wfc[tid] = s;
    sred[tid] = bf[tid] * sWc[tid];
    __syncthreads();
    for (int off = 256; off; off >>= 1) {
        if (tid < off) sred[tid] += sred[tid + off];
        __syncthreads();
    }
    if (tid == 0) *c0 = (float)NTt * sred[0] + bc[0];
}

// ---------------- QKV projection: [htgt;hsrc](2048x512) @ Wq + bq ----------------
__global__ __launch_bounds__(256)
void qkv_gemm(const float* __restrict__ htgt, const float* __restrict__ hsrc,
              const float* __restrict__ Wq, const float* __restrict__ bq,
              float* __restrict__ QK) {
    __shared__ float As[BK][BM];
    __shared__ float Bs[BK][BN];
    const int m0 = blockIdx.x * BM;
    const int n0 = blockIdx.y * BN;
    const int tid = threadIdx.x;
    const int tx = tid & 15, ty = tid >> 4;
    const float* Abase = (m0 < 1024) ? (htgt + (size_t)m0 * DD)
                                     : (hsrc + (size_t)(m0 - 1024) * DD);
    float acc[8][8];
#pragma unroll
    for (int i = 0; i < 8; ++i)
#pragma unroll
        for (int j = 0; j < 8; ++j) acc[i][j] = 0.f;

    const int ar = tid >> 1;
    const int ah = (tid & 1) * 4;
    const int bk = tid >> 5;
    const int bj = (tid & 31) * 4;

    for (int k0 = 0; k0 < DD; k0 += BK) {
        float4 av = *(const float4*)(Abase + (size_t)ar * DD + k0 + ah);
        float4 bv = *(const float4*)(Wq + (size_t)(k0 + bk) * DD + n0 + bj);
        As[ah + 0][ar] = av.x; As[ah + 1][ar] = av.y;
        As[ah + 2][ar] = av.z; As[ah + 3][ar] = av.w;
        *(float4*)&Bs[bk][bj] = bv;
        __syncthreads();
#pragma unroll
        for (int kk = 0; kk < BK; ++kk) {
            float4 a0 = *(const float4*)&As[kk][ty * 8];
            float4 a1 = *(const float4*)&As[kk][ty * 8 + 4];
            float4 b0 = *(const float4*)&Bs[kk][tx * 8];
            float4 b1 = *(const float4*)&Bs[kk][tx * 8 + 4];
            float a[8] = {a0.x, a0.y, a0.z, a0.w, a1.x, a1.y, a1.z, a1.w};
            float b[8] = {b0.x, b0.y, b0.z, b0.w, b1.x, b1.y, b1.z, b1.w};
#pragma unroll
            for (int i = 0; i < 8; ++i)
#pragma unroll
                for (int j = 0; j < 8; ++j)
                    acc[i][j] = fmaf(a[i], b[j], acc[i][j]);
        }
        __syncthreads();
    }
    const float scale = (m0 < 1024) ? 0.044194173824159216f : 1.0f;  // 1/sqrt(512)
#pragma unroll
    for (int i = 0; i < 8; ++i) {
        const int m = m0 + ty * 8 + i;
#pragma unroll
        for (int j = 0; j < 8; j += 4) {
            const int n = n0 + tx * 8 + j;
            float4 o;
            o.x = (acc[i][j + 0] + bq[n + 0]) * scale;
            o.y = (acc[i][j + 1] + bq[n + 1]) * scale;
            o.z = (acc[i][j + 2] + bq[n + 2]) * scale;
            o.w = (acc[i][j + 3] + bq[n + 3]) * scale;
            *(float4*)&QK[(size_t)m * DD + n] = o;
        }
    }
}

// ---------------- attention: one block per (b,t); softmax over s ----------------
__global__ __launch_bounds__(128)
void attn_kernel(const float* __restrict__ QK, float* __restrict__ attn,
                 float* __restrict__ colsum) {
    const int b = blockIdx.x & 7;
    const int t = blockIdx.x >> 3;
    const int tid = threadIdx.x;  // == s
    __shared__ float sQ[DD];
    __shared__ float sred[2];
    *(float4*)&sQ[tid * 4] = *(const float4*)&QK[(size_t)(t * BB + b) * DD + tid * 4];
    __syncthreads();
    const float* Krow = QK + (size_t)(1024 + tid * BB + b) * DD;
    float4 accv = make_float4(0.f, 0.f, 0.f, 0.f);
    for (int d = 0; d < DD; d += 4) {
        float4 kv = *(const float4*)(Krow + d);
        accv.x = fmaf(kv.x, sQ[d + 0], accv.x);
        accv.y = fmaf(kv.y, sQ[d + 1], accv.y);
        accv.z = fmaf(kv.z, sQ[d + 2], accv.z);
        accv.w = fmaf(kv.w, sQ[d + 3], accv.w);
    }
    const float dot = accv.x + accv.y + accv.z + accv.w;
    float m = dot;
    for (int off = 32; off; off >>= 1) m = fmaxf(m, __shfl_xor(m, off));
    if ((tid & 63) == 0) sred[tid >> 6] = m;
    __syncthreads();
    m = fmaxf(sred[0], sred[1]);
    const float p = __expf(dot - m);
    float ssum = p;
    for (int off = 32; off; off >>= 1) ssum += __shfl_xor(ssum, off);
    __syncthreads();
    if ((tid & 63) == 0) sred[tid >> 6] = ssum;
    __syncthreads();
    ssum = sred[0] + sred[1];
    const float a = p / ssum;
    attn[(size_t)(b * NTt + t) * NSs + tid] = a;
    atomicAdd(&colsum[b * NSs + tid], a);
}

// ---------------- a_copy[b] = sigmoid( sum_s colsum[b,s]*(K[b,s,:].wfc) + c0 ) ----------------
__global__ __launch_bounds__(128)
void acopy_kernel(const float* __restrict__ QK, const float* __restrict__ wfc,
                  const float* __restrict__ colsum, const float* __restrict__ c0,
                  float* __restrict__ ac) {
    const int b = blockIdx.x;
    const int tid = threadIdx.x;
    __shared__ float sW[DD];
    __shared__ float sred[2];
    *(float4*)&sW[tid * 4] = *(const float4*)&wfc[tid * 4];
    __syncthreads();
    const float* Krow = QK + (size_t)(1024 + tid * BB + b) * DD;
    float4 accv = make_float4(0.f, 0.f, 0.f, 0.f);
    for (int d = 0; d < DD; d += 4) {
        float4 kv = *(const float4*)(Krow + d);
        accv.x = fmaf(kv.x, sW[d + 0], accv.x);
        accv.y = fmaf(kv.y, sW[d + 1], accv.y);
        accv.z = fmaf(kv.z, sW[d + 2], accv.z);
        accv.w = fmaf(kv.w, sW[d + 3], accv.w);
    }
    const float kw = accv.x + accv.y + accv.z + accv.w;
    float val = colsum[b * NSs + tid] * kw;
    for (int off = 32; off; off >>= 1) val += __shfl_xor(val, off);
    if ((tid & 63) == 0) sred[tid >> 6] = val;
    __syncthreads();
    if (tid == 0) {
        const float z = sred[0] + sred[1] + *c0;
        ac[b] = 1.0f / (1.0f + __expf(-z));
    }
}

// ---------------- split htgt -> Ah/Al bf16 [1024][512] ----------------
__global__ __launch_bounds__(256)
void split_a(const float* __restrict__ A, ushortT* __restrict__ Ah,
             ushortT* __restrict__ Al) {
    const int gid = blockIdx.x * 256 + threadIdx.x;  // 131072 total, 4 elems each
    const size_t base = (size_t)gid * 4;
    float4 v = *(const float4*)(A + base);
    ushortT h[4], l[4];
    float x[4] = {v.x, v.y, v.z, v.w};
#pragma unroll
    for (int i = 0; i < 4; ++i) {
        h[i] = f2bf(x[i]);
        l[i] = f2bf(x[i] - bf2f(h[i]));
    }
    *(ushort4*)(Ah + base) = make_ushort4(h[0], h[1], h[2], h[3]);
    *(ushort4*)(Al + base) = make_ushort4(l[0], l[1], l[2], l[3]);
}

// ---------------- split + transpose Wg[512][32000] -> Bh/Bl bf16 [32000][512] ----------------
__global__ __launch_bounds__(256)
void split_bt(const float* __restrict__ Wg, ushortT* __restrict__ Bh,
              ushortT* __restrict__ Bl) {
    __shared__ float tile[32][65];
    const int n0 = blockIdx.x * 64;   // 500 blocks
    const int k0 = blockIdx.y * 32;   // 16 blocks
    const int tid = threadIdx.x;
    // load 32x64 floats, coalesced along n
    for (int c = tid; c < 512; c += 256) {
        const int r = c >> 4;          // k row 0..31
        const int q = (c & 15) * 4;    // n col
        float4 v = *(const float4*)(Wg + (size_t)(k0 + r) * VV + n0 + q);
        tile[r][q + 0] = v.x; tile[r][q + 1] = v.y;
        tile[r][q + 2] = v.z; tile[r][q + 3] = v.w;
    }
    __syncthreads();
    // write transposed: thread -> (n = tid>>2, ks = (tid&3)*8)
    const int n = tid >> 2;
    const int ks = (tid & 3) * 8;
    ushortT h[8], l[8];
#pragma unroll
    for (int j = 0; j < 8; ++j) {
        const float x = tile[ks + j][n];
        h[j] = f2bf(x);
        l[j] = f2bf(x - bf2f(h[j]));
    }
    const size_t ob = (size_t)(n0 + n) * 512 + k0 + ks;
    *(ushort4*)(Bh + ob)     = make_ushort4(h[0], h[1], h[2], h[3]);
    *(ushort4*)(Bh + ob + 4) = make_ushort4(h[4], h[5], h[6], h[7]);
    *(ushort4*)(Bl + ob)     = make_ushort4(l[0], l[1], l[2], l[3]);
    *(ushort4*)(Bl + ob + 4) = make_ushort4(l[4], l[5], l[6], l[7]);
}

// ---------------- p_gen GEMM via bf16-split MFMA ----------------
// out[m,n] = (1-ac[m%8]) * (sum_k htgt[m,k]*Wg[k,n] + bg[n])
// D ~= Ah*Bh + Ah*Bl + Al*Bh   (error ~2^-18 relative)
#define PK  32   // K-step
#define PKP 40   // padded LDS stride (80 B: 16B-aligned, 2-way bank alias = free)
__global__ __launch_bounds__(256)
void pgen_mfma(const ushortT* __restrict__ Ah, const ushortT* __restrict__ Al,
               const ushortT* __restrict__ Bh, const ushortT* __restrict__ Bl,
               const float* __restrict__ bg, const float* __restrict__ ac,
               float* __restrict__ out) {
    __shared__ __align__(16) ushortT sAh[128][PKP];
    __shared__ __align__(16) ushortT sAl[128][PKP];
    __shared__ __align__(16) ushortT sBh[128][PKP];
    __shared__ __align__(16) ushortT sBl[128][PKP];
    __shared__ float s_ac[8];

    const int m0 = blockIdx.x * 128;
    const int n0 = blockIdx.y * 128;
    const int tid = threadIdx.x;
    const int wid = tid >> 6;
    const int lane = tid & 63;
    const int wm = wid >> 1, wn = wid & 1;  // 2x2 wave grid, 64x64 each
    const int g = lane >> 4;                // 0..3
    const int lr = lane & 15;

    if (tid < 8) s_ac[tid] = 1.0f - ac[tid];

    f32x4 acc[4][4];
#pragma unroll
    for (int i = 0; i < 4; ++i)
#pragma unroll
        for (int j = 0; j < 4; ++j) acc[i][j] = (f32x4){0.f, 0.f, 0.f, 0.f};

    for (int k0 = 0; k0 < DD; k0 += PK) {
        // stage 2048 16B-chunks: A(hi,lo) 128x32 + B(hi,lo) 128x32
#pragma unroll
        for (int c8 = 0; c8 < 8; ++c8) {
            const int c = tid + c8 * 256;
            const int ab = c >> 10;
            const int cc = c & 1023;
            const int row = cc >> 3;
            const int mat = (cc >> 2) & 1;
            const int part = cc & 3;
            const ushortT* src;
            ushortT* dst;
            if (ab == 0) {
                src = (mat ? Al : Ah) + (size_t)(m0 + row) * 512 + k0 + part * 8;
                dst = (mat ? &sAl[0][0] : &sAh[0][0]) + row * PKP + part * 8;
            } else {
                src = (mat ? Bl : Bh) + (size_t)(n0 + row) * 512 + k0 + part * 8;
                dst = (mat ? &sBl[0][0] : &sBh[0][0]) + row * PKP + part * 8;
            }
            *(uint4*)dst = *(const uint4*)src;
        }
        __syncthreads();

        bf16x8 fah[4], fal[4], fbh[4], fbl[4];
#pragma unroll
        for (int i = 0; i < 4; ++i) {
            fah[i] = *(const bf16x8*)&sAh[wm * 64 + i * 16 + lr][g * 8];
            fal[i] = *(const bf16x8*)&sAl[wm * 64 + i * 16 + lr][g * 8];
            fbh[i] = *(const bf16x8*)&sBh[wn * 64 + i * 16 + lr][g * 8];
            fbl[i] = *(const bf16x8*)&sBl[wn * 64 + i * 16 + lr][g * 8];
        }
#pragma unroll
        for (int mi = 0; mi < 4; ++mi)
#pragma unroll
            for (int ni = 0; ni < 4; ++ni) {
                acc[mi][ni] = __builtin_amdgcn_mfma_f32_16x16x32_bf16(
                    fah[mi], fbh[ni], acc[mi][ni], 0, 0, 0);
                acc[mi][ni] = __builtin_amdgcn_mfma_f32_16x16x32_bf16(
                    fah[mi], fbl[ni], acc[mi][ni], 0, 0, 0);
                acc[mi][ni] = __builtin_amdgcn_mfma_f32_16x16x32_bf16(
                    fal[mi], fbh[ni], acc[mi][ni], 0, 0, 0);
            }
        __syncthreads();
    }

    // epilogue: C/D layout col=lane&15, row=(lane>>4)*4+r  [HW-verified m89/m91]
    float bgv[4];
#pragma unroll
    for (int i = 0; i < 4; ++i) bgv[i] = bg[n0 + wn * 64 + i * 16 + lr];
#pragma unroll
    for (int mi = 0; mi < 4; ++mi) {
#pragma unroll
        for (int r = 0; r < 4; ++r) {
            const int m = m0 + wm * 64 + mi * 16 + g * 4 + r;
            const float s = s_ac[(g * 4 + r) & 7];  // m%8 (m0,wm*64,mi*16 are mults of 8)
            const size_t ob = (size_t)m * VV + n0 + wn * 64 + lr;
#pragma unroll
            for (int ni = 0; ni < 4; ++ni) {
                out[ob + ni * 16] = s * (acc[mi][ni][r] + bgv[ni]);
            }
        }
    }
}

// ---------------- fp32 fallback p_gen GEMM (used if ws too small) ----------------
__global__ __launch_bounds__(256)
void pgen_gemm(const float* __restrict__ htgt, const float* __restrict__ Wg,
               const float* __restrict__ bg, const float* __restrict__ ac,
               float* __restrict__ out) {
    __shared__ float As[BK][BM];
    __shared__ float Bs[BK][BN];
    const int m0 = blockIdx.x * BM;
    const int n0 = blockIdx.y * BN;
    const int tid = threadIdx.x;
    const int tx = tid & 15, ty = tid >> 4;
    const float* Abase = htgt + (size_t)m0 * DD;
    float acc[8][8];
#pragma unroll
    for (int i = 0; i < 8; ++i)
#pragma unroll
        for (int j = 0; j < 8; ++j) acc[i][j] = 0.f;
    const int ar = tid >> 1;
    const int ah = (tid & 1) * 4;
    const int bk = tid >> 5;
    const int bj = (tid & 31) * 4;
    for (int k0 = 0; k0 < DD; k0 += BK) {
        float4 av = *(const float4*)(Abase + (size_t)ar * DD + k0 + ah);
        float4 bv = *(const float4*)(Wg + (size_t)(k0 + bk) * VV + n0 + bj);
        As[ah + 0][ar] = av.x; As[ah + 1][ar] = av.y;
        As[ah + 2][ar] = av.z; As[ah + 3][ar] = av.w;
        *(float4*)&Bs[bk][bj] = bv;
        __syncthreads();
#pragma unroll
        for (int kk = 0; kk < BK; ++kk) {
            float4 a0 = *(const float4*)&As[kk][ty * 8];
            float4 a1 = *(const float4*)&As[kk][ty * 8 + 4];
            float4 b0 = *(const float4*)&Bs[kk][tx * 8];
            float4 b1 = *(const float4*)&Bs[kk][tx * 8 + 4];
            float a[8] = {a0.x, a0.y, a0.z, a0.w, a1.x, a1.y, a1.z, a1.w};
            float b[8] = {b0.x, b0.y, b0.z, b0.w, b1.x, b1.y, b1.z, b1.w};
#pragma unroll
            for (int i = 0; i < 8; ++i)
#pragma unroll
                for (int j = 0; j < 8; ++j)
                    acc[i][j] = fmaf(a[i], b[j], acc[i][j]);
        }
        __syncthreads();
    }
    float sc[8];
#pragma unroll
    for (int i = 0; i < 8; ++i) sc[i] = 1.0f - ac[i];
#pragma unroll
    for (int i = 0; i < 8; ++i) {
        const int m = m0 + ty * 8 + i;
        const float s = sc[i];
#pragma unroll
        for (int j = 0; j < 8; j += 4) {
            const int n = n0 + tx * 8 + j;
            float4 o;
            o.x = s * (acc[i][j + 0] + bg[n + 0]);
            o.y = s * (acc[i][j + 1] + bg[n + 1]);
            o.z = s * (acc[i][j + 2] + bg[n + 2]);
            o.w = s * (acc[i][j + 3] + bg[n + 3]);
            *(float4*)&out[(size_t)m * VV + n] = o;
        }
    }
}

// ---------------- sparse copy-scatter ----------------
__global__ __launch_bounds__(256)
void scatter_kernel(const float* __restrict__ attn, const float* __restrict__ ac,
                    const int* __restrict__ src, float* __restrict__ out) {
    const int gid = blockIdx.x * 256 + threadIdx.x;  // 131072 total
    const int b = gid >> 14;
    const int rem = gid & 16383;
    const int t = rem >> 7;
    const int s = rem & 127;
    const float a = ac[b];
    const int v = src[s * BB + b];
    atomicAdd(&out[(size_t)(t * BB + b) * VV + v],
              a * attn[(size_t)(b * NTt + t) * NSs + s]);
}

extern "C" void kernel_launch(void* const* d_in, const int* in_sizes, int n_in,
                              void* d_out, int out_size, void* d_ws, size_t ws_size,
                              hipStream_t stream) {
    (void)in_sizes; (void)n_in; (void)out_size;
    const float* htgt = (const float*)d_in[0];
    const float* hsrc = (const float*)d_in[1];
    const int*   src  = (const int*)d_in[2];
    const float* Wq   = (const float*)d_in[3];
    const float* bq   = (const float*)d_in[4];
    const float* Wf   = (const float*)d_in[5];
    const float* bf   = (const float*)d_in[6];
    const float* Wg   = (const float*)d_in[7];
    const float* bg   = (const float*)d_in[8];
    const float* Wc   = (const float*)d_in[9];
    const float* bc   = (const float*)d_in[10];
    float* out = (float*)d_out;

    float* ws     = (float*)d_ws;
    float* QK     = ws;                      // 1,048,576 f
    float* attn   = QK + 2048 * 512;         // 131,072 f
    float* colsum = attn + 131072;           // 1,024 f
    float* wfc    = colsum + 1024;           // 512 f
    float* c0     = wfc + 512;               // 1 f (+7 pad)
    float* ac     = c0 + 8;                  // 8 f

    // bf16 region, 256B-aligned after the fp32 region
    size_t fp32_bytes = (size_t)(1048576 + 131072 + 1024 + 512 + 8 + 8) * 4;
    size_t base2 = (fp32_bytes + 255) & ~(size_t)255;
    ushortT* Ah = (ushortT*)((char*)d_ws + base2);
    ushortT* Al = Ah + (size_t)1024 * 512;
    ushortT* Bh = Al + (size_t)1024 * 512;
    ushortT* Bl = Bh + (size_t)32000 * 512;
    size_t need = base2 + 2 * (size_t)1024 * 512 * 2 + 2 * (size_t)32000 * 512 * 2;

    hipMemsetAsync(colsum, 0, 1024 * sizeof(float), stream);
    wfc_kernel<<<1, 512, 0, stream>>>(Wf, Wc, bf, bc, wfc, c0);
    qkv_gemm<<<dim3(16, 4), 256, 0, stream>>>(htgt, hsrc, Wq, bq, QK);
    attn_kernel<<<1024, 128, 0, stream>>>(QK, attn, colsum);
    acopy_kernel<<<8, 128, 0, stream>>>(QK, wfc, colsum, c0, ac);

    if (ws_size >= need) {
        split_a<<<512, 256, 0, stream>>>(htgt, Ah, Al);
        split_bt<<<dim3(500, 16), 256, 0, stream>>>(Wg, Bh, Bl);
        pgen_mfma<<<dim3(8, 250), 256, 0, stream>>>(Ah, Al, Bh, Bl, bg, ac, out);
    } else {
        pgen_gemm<<<dim3(8, 250), 256, 0, stream>>>(htgt, Wg, bg, ac, out);
    }
    scatter_kernel<<<512, 256, 0, stream>>>(attn, ac, src, out);
}

// Round 3
// 427.546 us; speedup vs baseline: 1.2404x; 1.2404x over previous
//
#include <hip/hip_runtime.h>
#include <math.h>

#define NTt 128
#define NSs 128
#define BB  8
#define DD  512
#define VV  32000

// bf16 helpers (manual RNE; inputs are normal floats, no NaN handling needed)
typedef unsigned short ushortT;
typedef unsigned int uintT;
__device__ __forceinline__ ushortT f2bf(float x) {
    uintT u = __float_as_uint(x);
    u = (u + 0x7fffu + ((u >> 16) & 1u)) >> 16;
    return (ushortT)u;
}
__device__ __forceinline__ float bf2f(ushortT h) {
    return __uint_as_float(((uintT)h) << 16);
}

typedef __attribute__((ext_vector_type(8))) short bf16x8;
typedef __attribute__((ext_vector_type(4))) float f32x4;

// ---------------- wfc[row] = Wf[row,:] . Wc  (parallel: wave per row) ----------------
__global__ __launch_bounds__(256)
void wfc_kernel(const float* __restrict__ Wf, const float* __restrict__ Wc,
                float* __restrict__ wfc) {
    __shared__ float sWc[DD];
    const int tid = threadIdx.x;
    sWc[tid] = Wc[tid];
    sWc[tid + 256] = Wc[tid + 256];
    __syncthreads();
    const int w = tid >> 6, lane = tid & 63;
    const int row = blockIdx.x * 4 + w;
    const float* r = Wf + (size_t)row * DD + lane * 8;
    float4 a = *(const float4*)r;
    float4 b = *(const float4*)(r + 4);
    const float* c = &sWc[lane * 8];
    float s = a.x * c[0] + a.y * c[1] + a.z * c[2] + a.w * c[3]
            + b.x * c[4] + b.y * c[5] + b.z * c[6] + b.w * c[7];
    for (int off = 32; off; off >>= 1) s += __shfl_xor(s, off);
    if (lane == 0) wfc[row] = s;
}

// ---------------- QKV projection: [htgt;hsrc](2048x512) @ Wq + bq, 64x64 tiles ----------------
#define QBM 64
#define QBN 64
#define QBK 16
__global__ __launch_bounds__(256)
void qkv_gemm(const float* __restrict__ htgt, const float* __restrict__ hsrc,
              const float* __restrict__ Wq, const float* __restrict__ bq,
              float* __restrict__ QK) {
    __shared__ float As[QBK][QBM];
    __shared__ float Bs[QBK][QBN];
    const int m0 = blockIdx.x * QBM;
    const int n0 = blockIdx.y * QBN;
    const int tid = threadIdx.x;
    const int tx = tid & 15, ty = tid >> 4;
    const float* Abase = (m0 < 1024) ? (htgt + (size_t)m0 * DD)
                                     : (hsrc + (size_t)(m0 - 1024) * DD);
    float acc[4][4];
#pragma unroll
    for (int i = 0; i < 4; ++i)
#pragma unroll
        for (int j = 0; j < 4; ++j) acc[i][j] = 0.f;

    const int ar = tid >> 2;        // 0..63 (A row)
    const int ak = (tid & 3) * 4;   // 0..12 (A k-quad)
    const int br = tid >> 4;        // 0..15 (B k-row)
    const int bc4 = (tid & 15) * 4; // 0..60 (B n-quad)

    for (int k0 = 0; k0 < DD; k0 += QBK) {
        float4 av = *(const float4*)(Abase + (size_t)ar * DD + k0 + ak);
        float4 bv = *(const float4*)(Wq + (size_t)(k0 + br) * DD + n0 + bc4);
        As[ak + 0][ar] = av.x; As[ak + 1][ar] = av.y;
        As[ak + 2][ar] = av.z; As[ak + 3][ar] = av.w;
        *(float4*)&Bs[br][bc4] = bv;
        __syncthreads();
#pragma unroll
        for (int kk = 0; kk < QBK; ++kk) {
            float4 a4 = *(const float4*)&As[kk][ty * 4];
            float4 b4 = *(const float4*)&Bs[kk][tx * 4];
            float a[4] = {a4.x, a4.y, a4.z, a4.w};
            float b[4] = {b4.x, b4.y, b4.z, b4.w};
#pragma unroll
            for (int i = 0; i < 4; ++i)
#pragma unroll
                for (int j = 0; j < 4; ++j)
                    acc[i][j] = fmaf(a[i], b[j], acc[i][j]);
        }
        __syncthreads();
    }
    const float scale = (m0 < 1024) ? 0.044194173824159216f : 1.0f;  // 1/sqrt(512)
    float4 bqv = *(const float4*)&bq[n0 + tx * 4];
#pragma unroll
    for (int i = 0; i < 4; ++i) {
        const int m = m0 + ty * 4 + i;
        float4 o;
        o.x = (acc[i][0] + bqv.x) * scale;
        o.y = (acc[i][1] + bqv.y) * scale;
        o.z = (acc[i][2] + bqv.z) * scale;
        o.w = (acc[i][3] + bqv.w) * scale;
        *(float4*)&QK[(size_t)m * DD + n0 + tx * 4] = o;
    }
}

// ---------------- attention: block = (b, 2 t-rows); softmax over s ----------------
__global__ __launch_bounds__(256)
void attn_kernel(const float* __restrict__ QK, float* __restrict__ attn,
                 float* __restrict__ colsum) {
    const int b = blockIdx.x & 7;
    const int tpair = blockIdx.x >> 3;       // 0..63
    const int tid = threadIdx.x;
    const int h = tid >> 7;                  // 0..1 (which t)
    const int s = tid & 127;
    const int t = tpair * 2 + h;
    __shared__ float sQ[2][DD];
    __shared__ float sred[8];
    sQ[h][s * 4 + 0] = 0.f;  // placate compiler; overwritten below
    *(float4*)&sQ[h][s * 4] = *(const float4*)&QK[(size_t)(t * BB + b) * DD + s * 4];
    __syncthreads();
    const float* Krow = QK + (size_t)(1024 + s * BB + b) * DD;
    const float* q = &sQ[h][0];
    float4 accv = make_float4(0.f, 0.f, 0.f, 0.f);
    for (int d = 0; d < DD; d += 4) {
        float4 kv = *(const float4*)(Krow + d);
        accv.x = fmaf(kv.x, q[d + 0], accv.x);
        accv.y = fmaf(kv.y, q[d + 1], accv.y);
        accv.z = fmaf(kv.z, q[d + 2], accv.z);
        accv.w = fmaf(kv.w, q[d + 3], accv.w);
    }
    const float dot = accv.x + accv.y + accv.z + accv.w;
    // per-wave reduce, then combine the 2 waves of this half
    float m = dot;
    for (int off = 32; off; off >>= 1) m = fmaxf(m, __shfl_xor(m, off));
    const int wv = tid >> 6;  // 0..3; waves {0,1}=h0, {2,3}=h1
    if ((tid & 63) == 0) sred[wv] = m;
    __syncthreads();
    m = fmaxf(sred[h * 2], sred[h * 2 + 1]);
    const float p = __expf(dot - m);
    float ssum = p;
    for (int off = 32; off; off >>= 1) ssum += __shfl_xor(ssum, off);
    __syncthreads();
    if ((tid & 63) == 0) sred[4 + wv] = ssum;
    __syncthreads();
    ssum = sred[4 + h * 2] + sred[4 + h * 2 + 1];
    const float a = p / ssum;
    attn[(size_t)(b * NTt + t) * NSs + s] = a;
    atomicAdd(&colsum[b * NSs + s], a);
}

// ---- a_copy[b] = sigmoid( sum_s colsum[b,s]*(K[b,s,:].wfc) + NT*(bf.Wc) + bc ) ----
__global__ __launch_bounds__(128)
void acopy_kernel(const float* __restrict__ QK, const float* __restrict__ wfc,
                  const float* __restrict__ colsum, const float* __restrict__ bf,
                  const float* __restrict__ Wc, const float* __restrict__ bc,
                  float* __restrict__ ac) {
    const int b = blockIdx.x;
    const int tid = threadIdx.x;
    __shared__ float sW[DD];
    __shared__ float sred[4];
    *(float4*)&sW[tid * 4] = *(const float4*)&wfc[tid * 4];
    __syncthreads();
    const float* Krow = QK + (size_t)(1024 + tid * BB + b) * DD;
    float4 accv = make_float4(0.f, 0.f, 0.f, 0.f);
    for (int d = 0; d < DD; d += 4) {
        float4 kv = *(const float4*)(Krow + d);
        accv.x = fmaf(kv.x, sW[d + 0], accv.x);
        accv.y = fmaf(kv.y, sW[d + 1], accv.y);
        accv.z = fmaf(kv.z, sW[d + 2], accv.z);
        accv.w = fmaf(kv.w, sW[d + 3], accv.w);
    }
    const float kw = accv.x + accv.y + accv.z + accv.w;
    float val = colsum[b * NSs + tid] * kw;
    float cw = 0.f;
#pragma unroll
    for (int j = 0; j < 4; ++j) cw += bf[tid + j * 128] * Wc[tid + j * 128];
    for (int off = 32; off; off >>= 1) {
        val += __shfl_xor(val, off);
        cw  += __shfl_xor(cw, off);
    }
    if ((tid & 63) == 0) { sred[tid >> 6] = val; sred[2 + (tid >> 6)] = cw; }
    __syncthreads();
    if (tid == 0) {
        const float z = sred[0] + sred[1] + (float)NTt * (sred[2] + sred[3]) + bc[0];
        ac[b] = 1.0f / (1.0f + __expf(-z));
    }
}

// ---------------- fused prep: split+transpose Wg -> Bh/Bl [32000][512]; split htgt -> Ah/Al ----------------
__global__ __launch_bounds__(256)
void split_prep(const float* __restrict__ Wg, const float* __restrict__ htgt,
                ushortT* __restrict__ Bh, ushortT* __restrict__ Bl,
                ushortT* __restrict__ Ah, ushortT* __restrict__ Al) {
    __shared__ float tile[32][65];
    const int bx = blockIdx.x;
    const int tid = threadIdx.x;
    if (bx < 8000) {
        const int n0 = (bx % 500) * 64;
        const int k0 = (bx / 500) * 32;
        for (int c = tid; c < 512; c += 256) {
            const int r = c >> 4;
            const int q = (c & 15) * 4;
            float4 v = *(const float4*)(Wg + (size_t)(k0 + r) * VV + n0 + q);
            tile[r][q + 0] = v.x; tile[r][q + 1] = v.y;
            tile[r][q + 2] = v.z; tile[r][q + 3] = v.w;
        }
        __syncthreads();
        const int n = tid >> 2;
        const int ks = (tid & 3) * 8;
        uintT h[8], l[8];
#pragma unroll
        for (int j = 0; j < 8; ++j) {
            const float x = tile[ks + j][n];
            h[j] = f2bf(x);
            l[j] = f2bf(x - bf2f((ushortT)h[j]));
        }
        uint4 hv, lv;
        hv.x = h[0] | (h[1] << 16); hv.y = h[2] | (h[3] << 16);
        hv.z = h[4] | (h[5] << 16); hv.w = h[6] | (h[7] << 16);
        lv.x = l[0] | (l[1] << 16); lv.y = l[2] | (l[3] << 16);
        lv.z = l[4] | (l[5] << 16); lv.w = l[6] | (l[7] << 16);
        const size_t ob = (size_t)(n0 + n) * 512 + k0 + ks;
        *(uint4*)(Bh + ob) = hv;
        *(uint4*)(Bl + ob) = lv;
    } else {
        // split_a: 65536 threads x 8 floats
        const int gid = (bx - 8000) * 256 + tid;
        const size_t base = (size_t)gid * 8;
        float4 v0 = *(const float4*)(htgt + base);
        float4 v1 = *(const float4*)(htgt + base + 4);
        float x[8] = {v0.x, v0.y, v0.z, v0.w, v1.x, v1.y, v1.z, v1.w};
        uintT h[8], l[8];
#pragma unroll
        for (int i = 0; i < 8; ++i) {
            h[i] = f2bf(x[i]);
            l[i] = f2bf(x[i] - bf2f((ushortT)h[i]));
        }
        uint4 hv, lv;
        hv.x = h[0] | (h[1] << 16); hv.y = h[2] | (h[3] << 16);
        hv.z = h[4] | (h[5] << 16); hv.w = h[6] | (h[7] << 16);
        lv.x = l[0] | (l[1] << 16); lv.y = l[2] | (l[3] << 16);
        lv.z = l[4] | (l[5] << 16); lv.w = l[6] | (l[7] << 16);
        *(uint4*)(Ah + base) = hv;
        *(uint4*)(Al + base) = lv;
    }
}

// ---------------- p_gen GEMM via bf16-split MFMA, XCD-chunked mapping ----------------
// out[m,n] = (1-ac[m%8]) * (sum_k htgt[m,k]*Wg[k,n] + bg[n])
#define PK  32
#define PKP 40   // padded LDS stride (80 B)
__global__ __launch_bounds__(256)
void pgen_mfma(const ushortT* __restrict__ Ah, const ushortT* __restrict__ Al,
               const ushortT* __restrict__ Bh, const ushortT* __restrict__ Bl,
               const float* __restrict__ bg, const float* __restrict__ ac,
               float* __restrict__ out) {
    __shared__ __align__(16) ushortT sAh[128][PKP];
    __shared__ __align__(16) ushortT sAl[128][PKP];
    __shared__ __align__(16) ushortT sBh[128][PKP];
    __shared__ __align__(16) ushortT sBl[128][PKP];
    __shared__ float s_ac[8];

    // XCD-chunked: HW assigns XCD = blockIdx % 8 round-robin. Give each XCD a
    // contiguous chunk of panel-major work so all 8 m-blocks of a B-panel stay
    // on one XCD's L2 (2000 % 8 == 0 -> bijective).
    const int idx = blockIdx.x;
    const int wg  = (idx & 7) * 250 + (idx >> 3);
    const int nb  = wg >> 3;   // 0..249
    const int mb  = wg & 7;    // 0..7
    const int m0 = mb * 128;
    const int n0 = nb * 128;

    const int tid = threadIdx.x;
    const int wid = tid >> 6;
    const int lane = tid & 63;
    const int wm = wid >> 1, wn = wid & 1;
    const int g = lane >> 4;
    const int lr = lane & 15;

    if (tid < 8) s_ac[tid] = 1.0f - ac[tid];

    f32x4 acc[4][4];
#pragma unroll
    for (int i = 0; i < 4; ++i)
#pragma unroll
        for (int j = 0; j < 4; ++j) acc[i][j] = (f32x4){0.f, 0.f, 0.f, 0.f};

    for (int k0 = 0; k0 < DD; k0 += PK) {
#pragma unroll
        for (int c8 = 0; c8 < 8; ++c8) {
            const int c = tid + c8 * 256;
            const int ab = c >> 10;
            const int cc = c & 1023;
            const int row = cc >> 3;
            const int mat = (cc >> 2) & 1;
            const int part = cc & 3;
            const ushortT* src;
            ushortT* dst;
            if (ab == 0) {
                src = (mat ? Al : Ah) + (size_t)(m0 + row) * 512 + k0 + part * 8;
                dst = (mat ? &sAl[0][0] : &sAh[0][0]) + row * PKP + part * 8;
            } else {
                src = (mat ? Bl : Bh) + (size_t)(n0 + row) * 512 + k0 + part * 8;
                dst = (mat ? &sBl[0][0] : &sBh[0][0]) + row * PKP + part * 8;
            }
            *(uint4*)dst = *(const uint4*)src;
        }
        __syncthreads();

        bf16x8 fah[4], fal[4], fbh[4], fbl[4];
#pragma unroll
        for (int i = 0; i < 4; ++i) {
            fah[i] = *(const bf16x8*)&sAh[wm * 64 + i * 16 + lr][g * 8];
            fal[i] = *(const bf16x8*)&sAl[wm * 64 + i * 16 + lr][g * 8];
            fbh[i] = *(const bf16x8*)&sBh[wn * 64 + i * 16 + lr][g * 8];
            fbl[i] = *(const bf16x8*)&sBl[wn * 64 + i * 16 + lr][g * 8];
        }
#pragma unroll
        for (int mi = 0; mi < 4; ++mi)
#pragma unroll
            for (int ni = 0; ni < 4; ++ni) {
                acc[mi][ni] = __builtin_amdgcn_mfma_f32_16x16x32_bf16(
                    fah[mi], fbh[ni], acc[mi][ni], 0, 0, 0);
                acc[mi][ni] = __builtin_amdgcn_mfma_f32_16x16x32_bf16(
                    fah[mi], fbl[ni], acc[mi][ni], 0, 0, 0);
                acc[mi][ni] = __builtin_amdgcn_mfma_f32_16x16x32_bf16(
                    fal[mi], fbh[ni], acc[mi][ni], 0, 0, 0);
            }
        __syncthreads();
    }

    // epilogue: C/D layout col=lane&15, row=(lane>>4)*4+r  [HW-verified m89/m91]
    float bgv[4];
#pragma unroll
    for (int i = 0; i < 4; ++i) bgv[i] = bg[n0 + wn * 64 + i * 16 + lr];
#pragma unroll
    for (int mi = 0; mi < 4; ++mi) {
#pragma unroll
        for (int r = 0; r < 4; ++r) {
            const int m = m0 + wm * 64 + mi * 16 + g * 4 + r;
            const float s = s_ac[(g * 4 + r) & 7];  // m%8
            const size_t ob = (size_t)m * VV + n0 + wn * 64 + lr;
#pragma unroll
            for (int ni = 0; ni < 4; ++ni) {
                out[ob + ni * 16] = s * (acc[mi][ni][r] + bgv[ni]);
            }
        }
    }
}

// ---------------- fp32 fallback p_gen GEMM (used if ws too small) ----------------
#define BM 128
#define BN 128
#define BK 8
__global__ __launch_bounds__(256)
void pgen_gemm(const float* __restrict__ htgt, const float* __restrict__ Wg,
               const float* __restrict__ bg, const float* __restrict__ ac,
               float* __restrict__ out) {
    __shared__ float As[BK][BM];
    __shared__ float Bs[BK][BN];
    const int m0 = blockIdx.x * BM;
    const int n0 = blockIdx.y * BN;
    const int tid = threadIdx.x;
    const int tx = tid & 15, ty = tid >> 4;
    const float* Abase = htgt + (size_t)m0 * DD;
    float acc[8][8];
#pragma unroll
    for (int i = 0; i < 8; ++i)
#pragma unroll
        for (int j = 0; j < 8; ++j) acc[i][j] = 0.f;
    const int ar = tid >> 1;
    const int ah = (tid & 1) * 4;
    const int bk = tid >> 5;
    const int bj = (tid & 31) * 4;
    for (int k0 = 0; k0 < DD; k0 += BK) {
        float4 av = *(const float4*)(Abase + (size_t)ar * DD + k0 + ah);
        float4 bv = *(const float4*)(Wg + (size_t)(k0 + bk) * VV + n0 + bj);
        As[ah + 0][ar] = av.x; As[ah + 1][ar] = av.y;
        As[ah + 2][ar] = av.z; As[ah + 3][ar] = av.w;
        *(float4*)&Bs[bk][bj] = bv;
        __syncthreads();
#pragma unroll
        for (int kk = 0; kk < BK; ++kk) {
            float4 a0 = *(const float4*)&As[kk][ty * 8];
            float4 a1 = *(const float4*)&As[kk][ty * 8 + 4];
            float4 b0 = *(const float4*)&Bs[kk][tx * 8];
            float4 b1 = *(const float4*)&Bs[kk][tx * 8 + 4];
            float a[8] = {a0.x, a0.y, a0.z, a0.w, a1.x, a1.y, a1.z, a1.w};
            float b[8] = {b0.x, b0.y, b0.z, b0.w, b1.x, b1.y, b1.z, b1.w};
#pragma unroll
            for (int i = 0; i < 8; ++i)
#pragma unroll
                for (int j = 0; j < 8; ++j)
                    acc[i][j] = fmaf(a[i], b[j], acc[i][j]);
        }
        __syncthreads();
    }
    float sc[8];
#pragma unroll
    for (int i = 0; i < 8; ++i) sc[i] = 1.0f - ac[i];
#pragma unroll
    for (int i = 0; i < 8; ++i) {
        const int m = m0 + ty * 8 + i;
        const float s = sc[i];
#pragma unroll
        for (int j = 0; j < 8; j += 4) {
            const int n = n0 + tx * 8 + j;
            float4 o;
            o.x = s * (acc[i][j + 0] + bg[n + 0]);
            o.y = s * (acc[i][j + 1] + bg[n + 1]);
            o.z = s * (acc[i][j + 2] + bg[n + 2]);
            o.w = s * (acc[i][j + 3] + bg[n + 3]);
            *(float4*)&out[(size_t)m * VV + n] = o;
        }
    }
}

// ---------------- sparse copy-scatter ----------------
__global__ __launch_bounds__(256)
void scatter_kernel(const float* __restrict__ attn, const float* __restrict__ ac,
                    const int* __restrict__ src, float* __restrict__ out) {
    const int gid = blockIdx.x * 256 + threadIdx.x;  // 131072 total
    const int b = gid >> 14;
    const int rem = gid & 16383;
    const int t = rem >> 7;
    const int s = rem & 127;
    const float a = ac[b];
    const int v = src[s * BB + b];
    atomicAdd(&out[(size_t)(t * BB + b) * VV + v],
              a * attn[(size_t)(b * NTt + t) * NSs + s]);
}

extern "C" void kernel_launch(void* const* d_in, const int* in_sizes, int n_in,
                              void* d_out, int out_size, void* d_ws, size_t ws_size,
                              hipStream_t stream) {
    (void)in_sizes; (void)n_in; (void)out_size;
    const float* htgt = (const float*)d_in[0];
    const float* hsrc = (const float*)d_in[1];
    const int*   src  = (const int*)d_in[2];
    const float* Wq   = (const float*)d_in[3];
    const float* bq   = (const float*)d_in[4];
    const float* Wf   = (const float*)d_in[5];
    const float* bf   = (const float*)d_in[6];
    const float* Wg   = (const float*)d_in[7];
    const float* bg   = (const float*)d_in[8];
    const float* Wc   = (const float*)d_in[9];
    const float* bc   = (const float*)d_in[10];
    float* out = (float*)d_out;

    float* ws     = (float*)d_ws;
    float* QK     = ws;                      // 1,048,576 f
    float* attn   = QK + 2048 * 512;         // 131,072 f
    float* colsum = attn + 131072;           // 1,024 f
    float* wfc    = colsum + 1024;           // 512 f
    float* ac     = wfc + 512;               // 8 f (+ pad)

    size_t fp32_bytes = (size_t)(1048576 + 131072 + 1024 + 512 + 16) * 4;
    size_t base2 = (fp32_bytes + 255) & ~(size_t)255;
    ushortT* Ah = (ushortT*)((char*)d_ws + base2);
    ushortT* Al = Ah + (size_t)1024 * 512;
    ushortT* Bh = Al + (size_t)1024 * 512;
    ushortT* Bl = Bh + (size_t)32000 * 512;
    size_t need = base2 + 2 * (size_t)1024 * 512 * 2 + 2 * (size_t)32000 * 512 * 2;

    hipMemsetAsync(colsum, 0, 1024 * sizeof(float), stream);
    wfc_kernel<<<128, 256, 0, stream>>>(Wf, Wc, wfc);
    if (ws_size >= need) {
        split_prep<<<8256, 256, 0, stream>>>(Wg, htgt, Bh, Bl, Ah, Al);
    }
    qkv_gemm<<<dim3(32, 8), 256, 0, stream>>>(htgt, hsrc, Wq, bq, QK);
    attn_kernel<<<512, 256, 0, stream>>>(QK, attn, colsum);
    acopy_kernel<<<8, 128, 0, stream>>>(QK, wfc, colsum, bf, Wc, bc, ac);

    if (ws_size >= need) {
        pgen_mfma<<<2000, 256, 0, stream>>>(Ah, Al, Bh, Bl, bg, ac, out);
    } else {
        pgen_gemm<<<dim3(8, 250), 256, 0, stream>>>(htgt, Wg, bg, ac, out);
    }
    scatter_kernel<<<512, 256, 0, stream>>>(attn, ac, src, out);
}

// Round 4
// 411.348 us; speedup vs baseline: 1.2893x; 1.0394x over previous
//
#include <hip/hip_runtime.h>
#include <math.h>

#define NTt 128
#define NSs 128
#define BB  8
#define DD  512
#define VV  32000

typedef unsigned short ushortT;
typedef unsigned int uintT;
__device__ __forceinline__ ushortT f2bf(float x) {
    uintT u = __float_as_uint(x);
    u = (u + 0x7fffu + ((u >> 16) & 1u)) >> 16;
    return (ushortT)u;
}
__device__ __forceinline__ float bf2f(ushortT h) {
    return __uint_as_float(((uintT)h) << 16);
}

typedef __attribute__((ext_vector_type(8))) short bf16x8;
typedef __attribute__((ext_vector_type(4))) float f32x4;

// async global->LDS, 16B per lane. LDS dest is WAVE-UNIFORM base (HW adds lane*16).
#define GLL16(g, l) __builtin_amdgcn_global_load_lds(                          \
    (const __attribute__((address_space(1))) unsigned int*)(g),                \
    (__attribute__((address_space(3))) unsigned int*)(l), 16, 0, 0)

#define LDSC 4096  // ushorts per 8KB tile chunk (128 rows x 32 k)

// ---------------- prep: pack Wg->Bpack, htgt->Apack (tile-linear hi/lo bf16), wfc ----------------
// Bpack layout: [panel 0..249][t 0..15][h 0..1][row 0..127][32 ushorts]
// Apack layout: [panel 0..7  ][t 0..15][h 0..1][row 0..127][32 ushorts]
__global__ __launch_bounds__(256)
void prep_kernel(const float* __restrict__ Wg, const float* __restrict__ htgt,
                 const float* __restrict__ Wf, const float* __restrict__ Wc,
                 ushortT* __restrict__ Bpack, ushortT* __restrict__ Apack,
                 float* __restrict__ wfc) {
    const int bx = blockIdx.x;
    const int tid = threadIdx.x;
    if (bx < 4000) {
        // ---- B pack: block = (panel p, kstep t); transpose 32k x 128n via LDS
        __shared__ float tile[32][129];
        const int p = bx >> 4, t = bx & 15;
        const int n0 = p * 128, k0 = t * 32;
#pragma unroll
        for (int i = 0; i < 4; ++i) {
            const int idx = tid + i * 256;       // 0..1023
            const int row = idx >> 5;            // k row 0..31
            const int c4 = (idx & 31) * 4;       // n col
            float4 v = *(const float4*)(Wg + (size_t)(k0 + row) * VV + n0 + c4);
            tile[row][c4 + 0] = v.x; tile[row][c4 + 1] = v.y;
            tile[row][c4 + 2] = v.z; tile[row][c4 + 3] = v.w;
        }
        __syncthreads();
        const int r = tid >> 1;                  // n-row within panel 0..127
        const int c2 = tid & 1;                  // which 16-k half
        uintT h[16], l[16];
#pragma unroll
        for (int j = 0; j < 16; ++j) {
            const float x = tile[c2 * 16 + j][r];
            h[j] = f2bf(x);
            l[j] = f2bf(x - bf2f((ushortT)h[j]));
        }
        ushortT* dh = Bpack + ((size_t)(p * 16 + t) * 2 + 0) * LDSC + r * 32 + c2 * 16;
        ushortT* dl = Bpack + ((size_t)(p * 16 + t) * 2 + 1) * LDSC + r * 32 + c2 * 16;
        uint4 hv0, hv1, lv0, lv1;
        hv0.x = h[0] | (h[1] << 16);  hv0.y = h[2] | (h[3] << 16);
        hv0.z = h[4] | (h[5] << 16);  hv0.w = h[6] | (h[7] << 16);
        hv1.x = h[8] | (h[9] << 16);  hv1.y = h[10] | (h[11] << 16);
        hv1.z = h[12] | (h[13] << 16); hv1.w = h[14] | (h[15] << 16);
        lv0.x = l[0] | (l[1] << 16);  lv0.y = l[2] | (l[3] << 16);
        lv0.z = l[4] | (l[5] << 16);  lv0.w = l[6] | (l[7] << 16);
        lv1.x = l[8] | (l[9] << 16);  lv1.y = l[10] | (l[11] << 16);
        lv1.z = l[12] | (l[13] << 16); lv1.w = l[14] | (l[15] << 16);
        *(uint4*)dh = hv0; *(uint4*)(dh + 8) = hv1;
        *(uint4*)dl = lv0; *(uint4*)(dl + 8) = lv1;
    } else if (bx < 4128) {
        // ---- A pack: block = (panel p, kstep t); rows along k -> direct reads
        const int idx = bx - 4000;
        const int p = idx >> 4, t = idx & 15;
        const int r = tid >> 1, c2 = tid & 1;
        const float* srcp = htgt + (size_t)(p * 128 + r) * DD + t * 32 + c2 * 16;
        uintT h[16], l[16];
#pragma unroll
        for (int q = 0; q < 4; ++q) {
            float4 v = *(const float4*)(srcp + q * 4);
            float xs[4] = {v.x, v.y, v.z, v.w};
#pragma unroll
            for (int j = 0; j < 4; ++j) {
                const int e = q * 4 + j;
                h[e] = f2bf(xs[j]);
                l[e] = f2bf(xs[j] - bf2f((ushortT)h[e]));
            }
        }
        ushortT* dh = Apack + ((size_t)(p * 16 + t) * 2 + 0) * LDSC + r * 32 + c2 * 16;
        ushortT* dl = Apack + ((size_t)(p * 16 + t) * 2 + 1) * LDSC + r * 32 + c2 * 16;
        uint4 hv0, hv1, lv0, lv1;
        hv0.x = h[0] | (h[1] << 16);  hv0.y = h[2] | (h[3] << 16);
        hv0.z = h[4] | (h[5] << 16);  hv0.w = h[6] | (h[7] << 16);
        hv1.x = h[8] | (h[9] << 16);  hv1.y = h[10] | (h[11] << 16);
        hv1.z = h[12] | (h[13] << 16); hv1.w = h[14] | (h[15] << 16);
        lv0.x = l[0] | (l[1] << 16);  lv0.y = l[2] | (l[3] << 16);
        lv0.z = l[4] | (l[5] << 16);  lv0.w = l[6] | (l[7] << 16);
        lv1.x = l[8] | (l[9] << 16);  lv1.y = l[10] | (l[11] << 16);
        lv1.z = l[12] | (l[13] << 16); lv1.w = l[14] | (l[15] << 16);
        *(uint4*)dh = hv0; *(uint4*)(dh + 8) = hv1;
        *(uint4*)dl = lv0; *(uint4*)(dl + 8) = lv1;
    } else {
        // ---- wfc[row] = Wf[row,:] . Wc  (wave per row)
        __shared__ float sWc[DD];
        sWc[tid] = Wc[tid];
        sWc[tid + 256] = Wc[tid + 256];
        __syncthreads();
        const int w = tid >> 6, lane = tid & 63;
        const int row = (bx - 4128) * 4 + w;
        const float* rp = Wf + (size_t)row * DD + lane * 8;
        float4 a = *(const float4*)rp;
        float4 b = *(const float4*)(rp + 4);
        const float* c = &sWc[lane * 8];
        float s = a.x * c[0] + a.y * c[1] + a.z * c[2] + a.w * c[3]
                + b.x * c[4] + b.y * c[5] + b.z * c[6] + b.w * c[7];
        for (int off = 32; off; off >>= 1) s += __shfl_xor(s, off);
        if (lane == 0) wfc[row] = s;
    }
}

// ---------------- QKV projection: [htgt;hsrc](2048x512) @ Wq + bq, 64x64 tiles ----------------
#define QBM 64
#define QBN 64
#define QBK 16
__global__ __launch_bounds__(256)
void qkv_gemm(const float* __restrict__ htgt, const float* __restrict__ hsrc,
              const float* __restrict__ Wq, const float* __restrict__ bq,
              float* __restrict__ QK) {
    __shared__ float As[QBK][QBM];
    __shared__ float Bs[QBK][QBN];
    const int m0 = blockIdx.x * QBM;
    const int n0 = blockIdx.y * QBN;
    const int tid = threadIdx.x;
    const int tx = tid & 15, ty = tid >> 4;
    const float* Abase = (m0 < 1024) ? (htgt + (size_t)m0 * DD)
                                     : (hsrc + (size_t)(m0 - 1024) * DD);
    float acc[4][4];
#pragma unroll
    for (int i = 0; i < 4; ++i)
#pragma unroll
        for (int j = 0; j < 4; ++j) acc[i][j] = 0.f;

    const int ar = tid >> 2;
    const int ak = (tid & 3) * 4;
    const int br = tid >> 4;
    const int bc4 = (tid & 15) * 4;

    for (int k0 = 0; k0 < DD; k0 += QBK) {
        float4 av = *(const float4*)(Abase + (size_t)ar * DD + k0 + ak);
        float4 bv = *(const float4*)(Wq + (size_t)(k0 + br) * DD + n0 + bc4);
        As[ak + 0][ar] = av.x; As[ak + 1][ar] = av.y;
        As[ak + 2][ar] = av.z; As[ak + 3][ar] = av.w;
        *(float4*)&Bs[br][bc4] = bv;
        __syncthreads();
#pragma unroll
        for (int kk = 0; kk < QBK; ++kk) {
            float4 a4 = *(const float4*)&As[kk][ty * 4];
            float4 b4 = *(const float4*)&Bs[kk][tx * 4];
            float a[4] = {a4.x, a4.y, a4.z, a4.w};
            float b[4] = {b4.x, b4.y, b4.z, b4.w};
#pragma unroll
            for (int i = 0; i < 4; ++i)
#pragma unroll
                for (int j = 0; j < 4; ++j)
                    acc[i][j] = fmaf(a[i], b[j], acc[i][j]);
        }
        __syncthreads();
    }
    const float scale = (m0 < 1024) ? 0.044194173824159216f : 1.0f;  // 1/sqrt(512)
    float4 bqv = *(const float4*)&bq[n0 + tx * 4];
#pragma unroll
    for (int i = 0; i < 4; ++i) {
        const int m = m0 + ty * 4 + i;
        float4 o;
        o.x = (acc[i][0] + bqv.x) * scale;
        o.y = (acc[i][1] + bqv.y) * scale;
        o.z = (acc[i][2] + bqv.z) * scale;
        o.w = (acc[i][3] + bqv.w) * scale;
        *(float4*)&QK[(size_t)m * DD + n0 + tx * 4] = o;
    }
}

// ---------------- attention: block = (b, 2 t-rows); softmax over s ----------------
__global__ __launch_bounds__(256)
void attn_kernel(const float* __restrict__ QK, float* __restrict__ attn) {
    const int b = blockIdx.x & 7;
    const int tpair = blockIdx.x >> 3;
    const int tid = threadIdx.x;
    const int h = tid >> 7;
    const int s = tid & 127;
    const int t = tpair * 2 + h;
    __shared__ float sQ[2][DD];
    __shared__ float sred[8];
    *(float4*)&sQ[h][s * 4] = *(const float4*)&QK[(size_t)(t * BB + b) * DD + s * 4];
    __syncthreads();
    const float* Krow = QK + (size_t)(1024 + s * BB + b) * DD;
    const float* q = &sQ[h][0];
    float4 accv = make_float4(0.f, 0.f, 0.f, 0.f);
    for (int d = 0; d < DD; d += 4) {
        float4 kv = *(const float4*)(Krow + d);
        accv.x = fmaf(kv.x, q[d + 0], accv.x);
        accv.y = fmaf(kv.y, q[d + 1], accv.y);
        accv.z = fmaf(kv.z, q[d + 2], accv.z);
        accv.w = fmaf(kv.w, q[d + 3], accv.w);
    }
    const float dot = accv.x + accv.y + accv.z + accv.w;
    float m = dot;
    for (int off = 32; off; off >>= 1) m = fmaxf(m, __shfl_xor(m, off));
    const int wv = tid >> 6;
    if ((tid & 63) == 0) sred[wv] = m;
    __syncthreads();
    m = fmaxf(sred[h * 2], sred[h * 2 + 1]);
    const float p = __expf(dot - m);
    float ssum = p;
    for (int off = 32; off; off >>= 1) ssum += __shfl_xor(ssum, off);
    __syncthreads();
    if ((tid & 63) == 0) sred[4 + wv] = ssum;
    __syncthreads();
    ssum = sred[4 + h * 2] + sred[4 + h * 2 + 1];
    attn[(size_t)(b * NTt + t) * NSs + s] = p / ssum;
}

// ---- a_copy[b] = sigmoid( sum_s colsum[b,s]*(K[b,s,:].wfc) + NT*(bf.Wc) + bc ) ----
// colsum computed inline (coalesced row sweep of attn).
__global__ __launch_bounds__(128)
void acopy_kernel(const float* __restrict__ QK, const float* __restrict__ wfc,
                  const float* __restrict__ attn, const float* __restrict__ bf,
                  const float* __restrict__ Wc, const float* __restrict__ bc,
                  float* __restrict__ ac) {
    const int b = blockIdx.x;
    const int tid = threadIdx.x;  // == s
    __shared__ float sW[DD];
    __shared__ float sred[4];
    *(float4*)&sW[tid * 4] = *(const float4*)&wfc[tid * 4];
    __syncthreads();
    // colsum[b][tid] = sum_t attn[b][t][tid]  (consecutive tid -> consecutive addr)
    float cs = 0.f;
    const float* arow = attn + (size_t)b * NTt * NSs + tid;
#pragma unroll 4
    for (int tq = 0; tq < NTt; ++tq) cs += arow[(size_t)tq * NSs];
    const float* Krow = QK + (size_t)(1024 + tid * BB + b) * DD;
    float4 accv = make_float4(0.f, 0.f, 0.f, 0.f);
    for (int d = 0; d < DD; d += 4) {
        float4 kv = *(const float4*)(Krow + d);
        accv.x = fmaf(kv.x, sW[d + 0], accv.x);
        accv.y = fmaf(kv.y, sW[d + 1], accv.y);
        accv.z = fmaf(kv.z, sW[d + 2], accv.z);
        accv.w = fmaf(kv.w, sW[d + 3], accv.w);
    }
    const float kw = accv.x + accv.y + accv.z + accv.w;
    float val = cs * kw;
    float cw = 0.f;
#pragma unroll
    for (int j = 0; j < 4; ++j) cw += bf[tid + j * 128] * Wc[tid + j * 128];
    for (int off = 32; off; off >>= 1) {
        val += __shfl_xor(val, off);
        cw  += __shfl_xor(cw, off);
    }
    if ((tid & 63) == 0) { sred[tid >> 6] = val; sred[2 + (tid >> 6)] = cw; }
    __syncthreads();
    if (tid == 0) {
        const float z = sred[0] + sred[1] + (float)NTt * (sred[2] + sred[3]) + bc[0];
        ac[b] = 1.0f / (1.0f + __expf(-z));
    }
}

// ---------------- p_gen GEMM via bf16-split MFMA + global_load_lds staging ----------------
// out[m,n] = (1-ac[m%8]) * (sum_k htgt[m,k]*Wg[k,n] + bg[n])
// 3 MFMA terms: Ah*Bh + Ah*Bl + Al*Bh  (error ~2^-18 rel)
__global__ __launch_bounds__(256)
void pgen_mfma(const ushortT* __restrict__ Apack, const ushortT* __restrict__ Bpack,
               const float* __restrict__ bg, const float* __restrict__ ac,
               float* __restrict__ out) {
    // 4 linear tile chunks: [Ah | Al | Bh | Bl], each 128 rows x 32 k (8KB)
    __shared__ __align__(16) ushortT sT[4 * LDSC];
    __shared__ float s_ac[8];

    // XCD-chunked mapping: all 8 m-blocks of a B-panel stay on one XCD's L2.
    const int idx = blockIdx.x;
    const int wg  = (idx & 7) * 250 + (idx >> 3);
    const int nb  = wg >> 3;   // 0..249
    const int mb  = wg & 7;    // 0..7
    const int m0 = mb * 128;
    const int n0 = nb * 128;

    const int tid = threadIdx.x;
    const int wid = tid >> 6;
    const int lane = tid & 63;
    const int wm = wid >> 1, wn = wid & 1;  // 2x2 wave grid, 64x64 each
    const int g = lane >> 4;
    const int lr = lane & 15;

    if (tid < 8) s_ac[tid] = 1.0f - ac[tid];

    // staging: wave wid copies chunk wid (0:Ah 1:Al 2:Bh 3:Bl), 8 x 1KB glls
    const ushortT* gsrc = ((wid < 2) ? (Apack + (size_t)mb * 16 * 2 * LDSC)
                                     : (Bpack + (size_t)nb * 16 * 2 * LDSC))
                          + (size_t)(wid & 1) * LDSC;
    ushortT* ldst = &sT[wid * LDSC];

    f32x4 acc[4][4];
#pragma unroll
    for (int i = 0; i < 4; ++i)
#pragma unroll
        for (int j = 0; j < 4; ++j) acc[i][j] = (f32x4){0.f, 0.f, 0.f, 0.f};

    for (int t = 0; t < 16; ++t) {
#pragma unroll
        for (int i = 0; i < 8; ++i) {
            GLL16(gsrc + i * 512 + lane * 8, ldst + i * 512);
        }
        __syncthreads();  // vmcnt(0) drained here by compiler

        bf16x8 fah[4], fal[4], fbh[4], fbl[4];
#pragma unroll
        for (int i = 0; i < 4; ++i) {
            const int arow = wm * 64 + i * 16 + lr;
            const int brow = wn * 64 + i * 16 + lr;
            fah[i] = *(const bf16x8*)&sT[0 * LDSC + arow * 32 + g * 8];
            fal[i] = *(const bf16x8*)&sT[1 * LDSC + arow * 32 + g * 8];
            fbh[i] = *(const bf16x8*)&sT[2 * LDSC + brow * 32 + g * 8];
            fbl[i] = *(const bf16x8*)&sT[3 * LDSC + brow * 32 + g * 8];
        }
#pragma unroll
        for (int mi = 0; mi < 4; ++mi)
#pragma unroll
            for (int ni = 0; ni < 4; ++ni) {
                acc[mi][ni] = __builtin_amdgcn_mfma_f32_16x16x32_bf16(
                    fah[mi], fbh[ni], acc[mi][ni], 0, 0, 0);
                acc[mi][ni] = __builtin_amdgcn_mfma_f32_16x16x32_bf16(
                    fah[mi], fbl[ni], acc[mi][ni], 0, 0, 0);
                acc[mi][ni] = __builtin_amdgcn_mfma_f32_16x16x32_bf16(
                    fal[mi], fbh[ni], acc[mi][ni], 0, 0, 0);
            }
        __syncthreads();
        gsrc += 2 * LDSC;
    }

    // epilogue: C/D layout col=lane&15, row=(lane>>4)*4+reg  [HW-verified m89/m91]
    float bgv[4];
#pragma unroll
    for (int i = 0; i < 4; ++i) bgv[i] = bg[n0 + wn * 64 + i * 16 + lr];
#pragma unroll
    for (int mi = 0; mi < 4; ++mi) {
#pragma unroll
        for (int r = 0; r < 4; ++r) {
            const int m = m0 + wm * 64 + mi * 16 + g * 4 + r;
            const float s = s_ac[(g * 4 + r) & 7];  // m%8
            const size_t ob = (size_t)m * VV + n0 + wn * 64 + lr;
#pragma unroll
            for (int ni = 0; ni < 4; ++ni) {
                out[ob + ni * 16] = s * (acc[mi][ni][r] + bgv[ni]);
            }
        }
    }
}

// ---------------- fp32 fallback p_gen GEMM (used if ws too small) ----------------
#define BM 128
#define BN 128
#define BK 8
__global__ __launch_bounds__(256)
void pgen_gemm(const float* __restrict__ htgt, const float* __restrict__ Wg,
               const float* __restrict__ bg, const float* __restrict__ ac,
               float* __restrict__ out) {
    __shared__ float As[BK][BM];
    __shared__ float Bs[BK][BN];
    const int m0 = blockIdx.x * BM;
    const int n0 = blockIdx.y * BN;
    const int tid = threadIdx.x;
    const int tx = tid & 15, ty = tid >> 4;
    const float* Abase = htgt + (size_t)m0 * DD;
    float acc[8][8];
#pragma unroll
    for (int i = 0; i < 8; ++i)
#pragma unroll
        for (int j = 0; j < 8; ++j) acc[i][j] = 0.f;
    const int ar = tid >> 1;
    const int ah = (tid & 1) * 4;
    const int bk = tid >> 5;
    const int bj = (tid & 31) * 4;
    for (int k0 = 0; k0 < DD; k0 += BK) {
        float4 av = *(const float4*)(Abase + (size_t)ar * DD + k0 + ah);
        float4 bv = *(const float4*)(Wg + (size_t)(k0 + bk) * VV + n0 + bj);
        As[ah + 0][ar] = av.x; As[ah + 1][ar] = av.y;
        As[ah + 2][ar] = av.z; As[ah + 3][ar] = av.w;
        *(float4*)&Bs[bk][bj] = bv;
        __syncthreads();
#pragma unroll
        for (int kk = 0; kk < BK; ++kk) {
            float4 a0 = *(const float4*)&As[kk][ty * 8];
            float4 a1 = *(const float4*)&As[kk][ty * 8 + 4];
            float4 b0 = *(const float4*)&Bs[kk][tx * 8];
            float4 b1 = *(const float4*)&Bs[kk][tx * 8 + 4];
            float a[8] = {a0.x, a0.y, a0.z, a0.w, a1.x, a1.y, a1.z, a1.w};
            float b[8] = {b0.x, b0.y, b0.z, b0.w, b1.x, b1.y, b1.z, b1.w};
#pragma unroll
            for (int i = 0; i < 8; ++i)
#pragma unroll
                for (int j = 0; j < 8; ++j)
                    acc[i][j] = fmaf(a[i], b[j], acc[i][j]);
        }
        __syncthreads();
    }
    float sc[8];
#pragma unroll
    for (int i = 0; i < 8; ++i) sc[i] = 1.0f - ac[i];
#pragma unroll
    for (int i = 0; i < 8; ++i) {
        const int m = m0 + ty * 8 + i;
        const float s = sc[i];
#pragma unroll
        for (int j = 0; j < 8; j += 4) {
            const int n = n0 + tx * 8 + j;
            float4 o;
            o.x = s * (acc[i][j + 0] + bg[n + 0]);
            o.y = s * (acc[i][j + 1] + bg[n + 1]);
            o.z = s * (acc[i][j + 2] + bg[n + 2]);
            o.w = s * (acc[i][j + 3] + bg[n + 3]);
            *(float4*)&out[(size_t)m * VV + n] = o;
        }
    }
}

// ---------------- sparse copy-scatter ----------------
__global__ __launch_bounds__(256)
void scatter_kernel(const float* __restrict__ attn, const float* __restrict__ ac,
                    const int* __restrict__ src, float* __restrict__ out) {
    const int gid = blockIdx.x * 256 + threadIdx.x;  // 131072 total
    const int b = gid >> 14;
    const int rem = gid & 16383;
    const int t = rem >> 7;
    const int s = rem & 127;
    const float a = ac[b];
    const int v = src[s * BB + b];
    atomicAdd(&out[(size_t)(t * BB + b) * VV + v],
              a * attn[(size_t)(b * NTt + t) * NSs + s]);
}

extern "C" void kernel_launch(void* const* d_in, const int* in_sizes, int n_in,
                              void* d_out, int out_size, void* d_ws, size_t ws_size,
                              hipStream_t stream) {
    (void)in_sizes; (void)n_in; (void)out_size;
    const float* htgt = (const float*)d_in[0];
    const float* hsrc = (const float*)d_in[1];
    const int*   src  = (const int*)d_in[2];
    const float* Wq   = (const float*)d_in[3];
    const float* bq   = (const float*)d_in[4];
    const float* Wf   = (const float*)d_in[5];
    const float* bf   = (const float*)d_in[6];
    const float* Wg   = (const float*)d_in[7];
    const float* bg   = (const float*)d_in[8];
    const float* Wc   = (const float*)d_in[9];
    const float* bc   = (const float*)d_in[10];
    float* out = (float*)d_out;

    float* ws   = (float*)d_ws;
    float* QK   = ws;                        // 1,048,576 f
    float* attn = QK + 2048 * 512;           // 131,072 f
    float* wfc  = attn + 131072;             // 512 f
    float* ac   = wfc + 512;                 // 8 f (+ pad)

    size_t fp32_bytes = (size_t)(1048576 + 131072 + 512 + 16) * 4;
    size_t base2 = (fp32_bytes + 255) & ~(size_t)255;
    ushortT* Apack = (ushortT*)((char*)d_ws + base2);               // 8*16*2*4096 = 1,048,576 us
    ushortT* Bpack = Apack + (size_t)8 * 16 * 2 * LDSC;             // 250*16*2*4096 = 32,768,000 us
    size_t need = base2 + ((size_t)8 * 16 * 2 * LDSC + (size_t)250 * 16 * 2 * LDSC) * 2;

    const bool use_mfma = (ws_size >= need);
    if (use_mfma) {
        prep_kernel<<<4256, 256, 0, stream>>>(Wg, htgt, Wf, Wc, Bpack, Apack, wfc);
    } else {
        // wfc still needed: run prep's wfc part only via the same kernel shape is
        // not possible; reuse acopy path requires wfc — compute with tiny grid.
        prep_kernel<<<dim3(128), 256, 0, stream>>>(Wg, htgt, Wf, Wc,
                                                   (ushortT*)ws, (ushortT*)ws, wfc);
    }
    qkv_gemm<<<dim3(32, 8), 256, 0, stream>>>(htgt, hsrc, Wq, bq, QK);
    attn_kernel<<<512, 256, 0, stream>>>(QK, attn);
    acopy_kernel<<<8, 128, 0, stream>>>(QK, wfc, attn, bf, Wc, bc, ac);

    if (use_mfma) {
        pgen_mfma<<<2000, 256, 0, stream>>>(Apack, Bpack, bg, ac, out);
    } else {
        pgen_gemm<<<dim3(8, 250), 256, 0, stream>>>(htgt, Wg, bg, ac, out);
    }
    scatter_kernel<<<512, 256, 0, stream>>>(attn, ac, src, out);
}

// Round 5
// 396.295 us; speedup vs baseline: 1.3383x; 1.0380x over previous
//
#include <hip/hip_runtime.h>
#include <math.h>

#define NTt 128
#define NSs 128
#define BB  8
#define DD  512
#define VV  32000

typedef unsigned short ushortT;
typedef unsigned int uintT;
__device__ __forceinline__ ushortT f2bf(float x) {
    uintT u = __float_as_uint(x);
    u = (u + 0x7fffu + ((u >> 16) & 1u)) >> 16;
    return (ushortT)u;
}
__device__ __forceinline__ float bf2f(ushortT h) {
    return __uint_as_float(((uintT)h) << 16);
}

typedef __attribute__((ext_vector_type(8))) short bf16x8;
typedef __attribute__((ext_vector_type(4))) float f32x4;

// async global->LDS, 16B per lane. LDS dest is WAVE-UNIFORM base (HW adds lane*16).
#define GLL16(g, l) __builtin_amdgcn_global_load_lds(                          \
    (const __attribute__((address_space(1))) unsigned int*)(g),                \
    (__attribute__((address_space(3))) unsigned int*)(l), 16, 0, 0)

#define LDSC 4096  // ushorts per 8KB tile chunk (128 rows x 32 k)

// Packed chunk layout (A and B identical): chunk[pgi*8 + e] =
//   value(row = (pgi>>6)*16 + (pgi&15), k_local = ((pgi>>4)&3)*8 + e),  pgi in [0,512)
// This is EXACTLY the order wave-lane l reads fragment f: offset f*512 + l*8
// -> ds_read_b128 is linear in lane (conflict-free), GLL16 source is linear in lane.

// ---------------- prep: pack Wg->Bpack, htgt->Apack (lane-order hi/lo bf16), wfc ----------------
// Bpack: [panel 0..249][t 0..15][hi/lo][packed 4096]   Apack: [panel 0..7][t][hi/lo][4096]
__global__ __launch_bounds__(256)
void prep_kernel(const float* __restrict__ Wg, const float* __restrict__ htgt,
                 const float* __restrict__ Wf, const float* __restrict__ Wc,
                 ushortT* __restrict__ Bpack, ushortT* __restrict__ Apack,
                 float* __restrict__ wfc) {
    const int bx = blockIdx.x;
    const int tid = threadIdx.x;
    if (bx < 4000) {
        // ---- B pack: block = (panel p, kstep t); transpose 32k x 128n via LDS
        __shared__ float tile[32][129];
        const int p = bx >> 4, t = bx & 15;
        const int n0 = p * 128, k0 = t * 32;
#pragma unroll
        for (int i = 0; i < 4; ++i) {
            const int idx = tid + i * 256;       // 0..1023
            const int row = idx >> 5;            // k row 0..31
            const int c4 = (idx & 31) * 4;       // n col
            float4 v = *(const float4*)(Wg + (size_t)(k0 + row) * VV + n0 + c4);
            tile[row][c4 + 0] = v.x; tile[row][c4 + 1] = v.y;
            tile[row][c4 + 2] = v.z; tile[row][c4 + 3] = v.w;
        }
        __syncthreads();
        const size_t cb = ((size_t)(p * 16 + t) * 2) * LDSC;  // hi chunk base
#pragma unroll
        for (int h2 = 0; h2 < 2; ++h2) {
            const int pgi = h2 * 256 + tid;
            const int fi  = pgi >> 6;
            const int gg  = (pgi >> 4) & 3;
            const int lr2 = pgi & 15;
            const int row = fi * 16 + lr2;       // n-row within panel
            uintT h[8], l[8];
#pragma unroll
            for (int j = 0; j < 8; ++j) {
                const float x = tile[gg * 8 + j][row];
                h[j] = f2bf(x);
                l[j] = f2bf(x - bf2f((ushortT)h[j]));
            }
            uint4 hv, lv;
            hv.x = h[0] | (h[1] << 16); hv.y = h[2] | (h[3] << 16);
            hv.z = h[4] | (h[5] << 16); hv.w = h[6] | (h[7] << 16);
            lv.x = l[0] | (l[1] << 16); lv.y = l[2] | (l[3] << 16);
            lv.z = l[4] | (l[5] << 16); lv.w = l[6] | (l[7] << 16);
            *(uint4*)(Bpack + cb + (size_t)pgi * 8) = hv;
            *(uint4*)(Bpack + cb + LDSC + (size_t)pgi * 8) = lv;
        }
    } else if (bx < 4128) {
        // ---- A pack: block = (panel p, kstep t)
        const int idx2 = bx - 4000;
        const int p = idx2 >> 4, t = idx2 & 15;
        const size_t cb = ((size_t)(p * 16 + t) * 2) * LDSC;
#pragma unroll
        for (int h2 = 0; h2 < 2; ++h2) {
            const int pgi = h2 * 256 + tid;
            const int fi  = pgi >> 6;
            const int gg  = (pgi >> 4) & 3;
            const int lr2 = pgi & 15;
            const int row = fi * 16 + lr2;       // m-row within panel
            const float* srcp = htgt + (size_t)(p * 128 + row) * DD + t * 32 + gg * 8;
            float4 v0 = *(const float4*)srcp;
            float4 v1 = *(const float4*)(srcp + 4);
            float xs[8] = {v0.x, v0.y, v0.z, v0.w, v1.x, v1.y, v1.z, v1.w};
            uintT h[8], l[8];
#pragma unroll
            for (int j = 0; j < 8; ++j) {
                h[j] = f2bf(xs[j]);
                l[j] = f2bf(xs[j] - bf2f((ushortT)h[j]));
            }
            uint4 hv, lv;
            hv.x = h[0] | (h[1] << 16); hv.y = h[2] | (h[3] << 16);
            hv.z = h[4] | (h[5] << 16); hv.w = h[6] | (h[7] << 16);
            lv.x = l[0] | (l[1] << 16); lv.y = l[2] | (l[3] << 16);
            lv.z = l[4] | (l[5] << 16); lv.w = l[6] | (l[7] << 16);
            *(uint4*)(Apack + cb + (size_t)pgi * 8) = hv;
            *(uint4*)(Apack + cb + LDSC + (size_t)pgi * 8) = lv;
        }
    } else {
        // ---- wfc[row] = Wf[row,:] . Wc  (wave per row)
        __shared__ float sWc[DD];
        sWc[tid] = Wc[tid];
        sWc[tid + 256] = Wc[tid + 256];
        __syncthreads();
        const int w = tid >> 6, lane = tid & 63;
        const int row = (bx - 4128) * 4 + w;
        const float* rp = Wf + (size_t)row * DD + lane * 8;
        float4 a = *(const float4*)rp;
        float4 b = *(const float4*)(rp + 4);
        const float* c = &sWc[lane * 8];
        float s = a.x * c[0] + a.y * c[1] + a.z * c[2] + a.w * c[3]
                + b.x * c[4] + b.y * c[5] + b.z * c[6] + b.w * c[7];
        for (int off = 32; off; off >>= 1) s += __shfl_xor(s, off);
        if (lane == 0) wfc[row] = s;
    }
}

// ---------------- wfc-only (fallback path) ----------------
__global__ __launch_bounds__(256)
void wfc_only_kernel(const float* __restrict__ Wf, const float* __restrict__ Wc,
                     float* __restrict__ wfc) {
    __shared__ float sWc[DD];
    const int tid = threadIdx.x;
    sWc[tid] = Wc[tid];
    sWc[tid + 256] = Wc[tid + 256];
    __syncthreads();
    const int w = tid >> 6, lane = tid & 63;
    const int row = blockIdx.x * 4 + w;
    const float* rp = Wf + (size_t)row * DD + lane * 8;
    float4 a = *(const float4*)rp;
    float4 b = *(const float4*)(rp + 4);
    const float* c = &sWc[lane * 8];
    float s = a.x * c[0] + a.y * c[1] + a.z * c[2] + a.w * c[3]
            + b.x * c[4] + b.y * c[5] + b.z * c[6] + b.w * c[7];
    for (int off = 32; off; off >>= 1) s += __shfl_xor(s, off);
    if (lane == 0) wfc[row] = s;
}

// ---------------- QKV projection: [htgt;hsrc](2048x512) @ Wq + bq, 64x64 tiles ----------------
#define QBM 64
#define QBN 64
#define QBK 16
__global__ __launch_bounds__(256)
void qkv_gemm(const float* __restrict__ htgt, const float* __restrict__ hsrc,
              const float* __restrict__ Wq, const float* __restrict__ bq,
              float* __restrict__ QK) {
    __shared__ float As[QBK][QBM];
    __shared__ float Bs[QBK][QBN];
    const int m0 = blockIdx.x * QBM;
    const int n0 = blockIdx.y * QBN;
    const int tid = threadIdx.x;
    const int tx = tid & 15, ty = tid >> 4;
    const float* Abase = (m0 < 1024) ? (htgt + (size_t)m0 * DD)
                                     : (hsrc + (size_t)(m0 - 1024) * DD);
    float acc[4][4];
#pragma unroll
    for (int i = 0; i < 4; ++i)
#pragma unroll
        for (int j = 0; j < 4; ++j) acc[i][j] = 0.f;

    const int ar = tid >> 2;
    const int ak = (tid & 3) * 4;
    const int br = tid >> 4;
    const int bc4 = (tid & 15) * 4;

    for (int k0 = 0; k0 < DD; k0 += QBK) {
        float4 av = *(const float4*)(Abase + (size_t)ar * DD + k0 + ak);
        float4 bv = *(const float4*)(Wq + (size_t)(k0 + br) * DD + n0 + bc4);
        As[ak + 0][ar] = av.x; As[ak + 1][ar] = av.y;
        As[ak + 2][ar] = av.z; As[ak + 3][ar] = av.w;
        *(float4*)&Bs[br][bc4] = bv;
        __syncthreads();
#pragma unroll
        for (int kk = 0; kk < QBK; ++kk) {
            float4 a4 = *(const float4*)&As[kk][ty * 4];
            float4 b4 = *(const float4*)&Bs[kk][tx * 4];
            float a[4] = {a4.x, a4.y, a4.z, a4.w};
            float b[4] = {b4.x, b4.y, b4.z, b4.w};
#pragma unroll
            for (int i = 0; i < 4; ++i)
#pragma unroll
                for (int j = 0; j < 4; ++j)
                    acc[i][j] = fmaf(a[i], b[j], acc[i][j]);
        }
        __syncthreads();
    }
    const float scale = (m0 < 1024) ? 0.044194173824159216f : 1.0f;  // 1/sqrt(512)
    float4 bqv = *(const float4*)&bq[n0 + tx * 4];
#pragma unroll
    for (int i = 0; i < 4; ++i) {
        const int m = m0 + ty * 4 + i;
        float4 o;
        o.x = (acc[i][0] + bqv.x) * scale;
        o.y = (acc[i][1] + bqv.y) * scale;
        o.z = (acc[i][2] + bqv.z) * scale;
        o.w = (acc[i][3] + bqv.w) * scale;
        *(float4*)&QK[(size_t)m * DD + n0 + tx * 4] = o;
    }
}

// ---------------- attention: block = (b, 2 t-rows); softmax over s ----------------
__global__ __launch_bounds__(256)
void attn_kernel(const float* __restrict__ QK, float* __restrict__ attn) {
    const int b = blockIdx.x & 7;
    const int tpair = blockIdx.x >> 3;
    const int tid = threadIdx.x;
    const int h = tid >> 7;
    const int s = tid & 127;
    const int t = tpair * 2 + h;
    __shared__ float sQ[2][DD];
    __shared__ float sred[8];
    *(float4*)&sQ[h][s * 4] = *(const float4*)&QK[(size_t)(t * BB + b) * DD + s * 4];
    __syncthreads();
    const float* Krow = QK + (size_t)(1024 + s * BB + b) * DD;
    const float* q = &sQ[h][0];
    float4 accv = make_float4(0.f, 0.f, 0.f, 0.f);
    for (int d = 0; d < DD; d += 4) {
        float4 kv = *(const float4*)(Krow + d);
        accv.x = fmaf(kv.x, q[d + 0], accv.x);
        accv.y = fmaf(kv.y, q[d + 1], accv.y);
        accv.z = fmaf(kv.z, q[d + 2], accv.z);
        accv.w = fmaf(kv.w, q[d + 3], accv.w);
    }
    const float dot = accv.x + accv.y + accv.z + accv.w;
    float m = dot;
    for (int off = 32; off; off >>= 1) m = fmaxf(m, __shfl_xor(m, off));
    const int wv = tid >> 6;
    if ((tid & 63) == 0) sred[wv] = m;
    __syncthreads();
    m = fmaxf(sred[h * 2], sred[h * 2 + 1]);
    const float p = __expf(dot - m);
    float ssum = p;
    for (int off = 32; off; off >>= 1) ssum += __shfl_xor(ssum, off);
    __syncthreads();
    if ((tid & 63) == 0) sred[4 + wv] = ssum;
    __syncthreads();
    ssum = sred[4 + h * 2] + sred[4 + h * 2 + 1];
    attn[(size_t)(b * NTt + t) * NSs + s] = p / ssum;
}

// ---- a_copy[b] = sigmoid( sum_s colsum[b,s]*(K[b,s,:].wfc) + NT*(bf.Wc) + bc ) ----
__global__ __launch_bounds__(128)
void acopy_kernel(const float* __restrict__ QK, const float* __restrict__ wfc,
                  const float* __restrict__ attn, const float* __restrict__ bf,
                  const float* __restrict__ Wc, const float* __restrict__ bc,
                  float* __restrict__ ac) {
    const int b = blockIdx.x;
    const int tid = threadIdx.x;  // == s
    __shared__ float sW[DD];
    __shared__ float sred[4];
    *(float4*)&sW[tid * 4] = *(const float4*)&wfc[tid * 4];
    __syncthreads();
    float cs = 0.f;
    const float* arow = attn + (size_t)b * NTt * NSs + tid;
#pragma unroll 4
    for (int tq = 0; tq < NTt; ++tq) cs += arow[(size_t)tq * NSs];
    const float* Krow = QK + (size_t)(1024 + tid * BB + b) * DD;
    float4 accv = make_float4(0.f, 0.f, 0.f, 0.f);
    for (int d = 0; d < DD; d += 4) {
        float4 kv = *(const float4*)(Krow + d);
        accv.x = fmaf(kv.x, sW[d + 0], accv.x);
        accv.y = fmaf(kv.y, sW[d + 1], accv.y);
        accv.z = fmaf(kv.z, sW[d + 2], accv.z);
        accv.w = fmaf(kv.w, sW[d + 3], accv.w);
    }
    const float kw = accv.x + accv.y + accv.z + accv.w;
    float val = cs * kw;
    float cw = 0.f;
#pragma unroll
    for (int j = 0; j < 4; ++j) cw += bf[tid + j * 128] * Wc[tid + j * 128];
    for (int off = 32; off; off >>= 1) {
        val += __shfl_xor(val, off);
        cw  += __shfl_xor(cw, off);
    }
    if ((tid & 63) == 0) { sred[tid >> 6] = val; sred[2 + (tid >> 6)] = cw; }
    __syncthreads();
    if (tid == 0) {
        const float z = sred[0] + sred[1] + (float)NTt * (sred[2] + sred[3]) + bc[0];
        ac[b] = 1.0f / (1.0f + __expf(-z));
    }
}

// ---------------- p_gen GEMM: bf16-split MFMA, 2-phase prefetch + lane-order LDS ----------------
// out[m,n] = (1-ac[m%8]) * (sum_k htgt[m,k]*Wg[k,n] + bg[n])
// 3 MFMA terms: Ah*Bh + Ah*Bl + Al*Bh  (error ~2^-18 rel)
__global__ __launch_bounds__(256)
void pgen_mfma(const ushortT* __restrict__ Apack, const ushortT* __restrict__ Bpack,
               const float* __restrict__ bg, const float* __restrict__ ac,
               float* __restrict__ out) {
    // double-buffered: each buffer = 4 chunks [Ah | Al | Bh | Bl], 8KB each
    __shared__ __align__(16) ushortT sT[2][4 * LDSC];
    __shared__ float s_ac[8];

    // XCD-chunked mapping: all 8 m-blocks of a B-panel on one XCD's L2 (2000%8==0).
    const int idx = blockIdx.x;
    const int wg  = (idx & 7) * 250 + (idx >> 3);
    const int nb  = wg >> 3;   // 0..249
    const int mb  = wg & 7;    // 0..7
    const int m0 = mb * 128;
    const int n0 = nb * 128;

    const int tid = threadIdx.x;
    const int wid = tid >> 6;
    const int lane = tid & 63;
    const int wm = wid >> 1, wn = wid & 1;  // 2x2 wave grid, 64x64 each
    const int g = lane >> 4;
    const int lr = lane & 15;

    if (tid < 8) s_ac[tid] = 1.0f - ac[tid];

    // wave wid stages chunk type wid (0:Ah 1:Al 2:Bh 3:Bl)
    const ushortT* gs = ((wid < 2) ? (Apack + (size_t)mb * 16 * 2 * LDSC)
                                   : (Bpack + (size_t)nb * 16 * 2 * LDSC))
                        + (size_t)(wid & 1) * LDSC;
    ushortT* ld0 = &sT[0][wid * LDSC];
    ushortT* ld1 = &sT[1][wid * LDSC];

    f32x4 acc[4][4];
#pragma unroll
    for (int i = 0; i < 4; ++i)
#pragma unroll
        for (int j = 0; j < 4; ++j) acc[i][j] = (f32x4){0.f, 0.f, 0.f, 0.f};

    // one compute step: MFMA on buffer Bp; optionally stage next K-step into nxt first.
    auto step = [&](const ushortT* Bp, ushortT* nxt, bool stage) {
        if (stage) {
#pragma unroll
            for (int i = 0; i < 8; ++i)
                GLL16(gs + i * 512 + lane * 8, nxt + i * 512);
            gs += 2 * LDSC;
        }
        bf16x8 fah[4], fal[4], fbh[4], fbl[4];
#pragma unroll
        for (int i = 0; i < 4; ++i) {
            // lane-order layout: fragment f at chunk offset f*512 + lane*8
            fah[i] = *(const bf16x8*)&Bp[0 * LDSC + (wm * 4 + i) * 512 + lane * 8];
            fal[i] = *(const bf16x8*)&Bp[1 * LDSC + (wm * 4 + i) * 512 + lane * 8];
            fbh[i] = *(const bf16x8*)&Bp[2 * LDSC + (wn * 4 + i) * 512 + lane * 8];
            fbl[i] = *(const bf16x8*)&Bp[3 * LDSC + (wn * 4 + i) * 512 + lane * 8];
        }
#pragma unroll
        for (int mi = 0; mi < 4; ++mi)
#pragma unroll
            for (int ni = 0; ni < 4; ++ni) {
                acc[mi][ni] = __builtin_amdgcn_mfma_f32_16x16x32_bf16(
                    fah[mi], fbh[ni], acc[mi][ni], 0, 0, 0);
                acc[mi][ni] = __builtin_amdgcn_mfma_f32_16x16x32_bf16(
                    fah[mi], fbl[ni], acc[mi][ni], 0, 0, 0);
                acc[mi][ni] = __builtin_amdgcn_mfma_f32_16x16x32_bf16(
                    fal[mi], fbh[ni], acc[mi][ni], 0, 0, 0);
            }
        // single barrier per K-step: publishes the staged buffer AND proves all
        // waves finished reading Bp (safe to overwrite next step).
        __syncthreads();
    };

    // prologue: stage t=0 into buf0
#pragma unroll
    for (int i = 0; i < 8; ++i)
        GLL16(gs + i * 512 + lane * 8, ld0 + i * 512);
    gs += 2 * LDSC;
    __syncthreads();

    for (int tp = 0; tp < 8; ++tp) {
        step(&sT[0][0], ld1, true);      // compute t=2tp,   stage t=2tp+1
        step(&sT[1][0], ld0, tp < 7);    // compute t=2tp+1, stage t=2tp+2
    }

    // epilogue: C/D layout col=lane&15, row=(lane>>4)*4+reg  [HW-verified m89/m91]
    float bgv[4];
#pragma unroll
    for (int i = 0; i < 4; ++i) bgv[i] = bg[n0 + wn * 64 + i * 16 + lr];
#pragma unroll
    for (int mi = 0; mi < 4; ++mi) {
#pragma unroll
        for (int r = 0; r < 4; ++r) {
            const int m = m0 + wm * 64 + mi * 16 + g * 4 + r;
            const float s = s_ac[(g * 4 + r) & 7];  // m%8
            const size_t ob = (size_t)m * VV + n0 + wn * 64 + lr;
#pragma unroll
            for (int ni = 0; ni < 4; ++ni) {
                out[ob + ni * 16] = s * (acc[mi][ni][r] + bgv[ni]);
            }
        }
    }
}

// ---------------- fp32 fallback p_gen GEMM (used if ws too small) ----------------
#define BM 128
#define BN 128
#define BK 8
__global__ __launch_bounds__(256)
void pgen_gemm(const float* __restrict__ htgt, const float* __restrict__ Wg,
               const float* __restrict__ bg, const float* __restrict__ ac,
               float* __restrict__ out) {
    __shared__ float As[BK][BM];
    __shared__ float Bs[BK][BN];
    const int m0 = blockIdx.x * BM;
    const int n0 = blockIdx.y * BN;
    const int tid = threadIdx.x;
    const int tx = tid & 15, ty = tid >> 4;
    const float* Abase = htgt + (size_t)m0 * DD;
    float acc[8][8];
#pragma unroll
    for (int i = 0; i < 8; ++i)
#pragma unroll
        for (int j = 0; j < 8; ++j) acc[i][j] = 0.f;
    const int ar = tid >> 1;
    const int ah = (tid & 1) * 4;
    const int bk = tid >> 5;
    const int bj = (tid & 31) * 4;
    for (int k0 = 0; k0 < DD; k0 += BK) {
        float4 av = *(const float4*)(Abase + (size_t)ar * DD + k0 + ah);
        float4 bv = *(const float4*)(Wg + (size_t)(k0 + bk) * VV + n0 + bj);
        As[ah + 0][ar] = av.x; As[ah + 1][ar] = av.y;
        As[ah + 2][ar] = av.z; As[ah + 3][ar] = av.w;
        *(float4*)&Bs[bk][bj] = bv;
        __syncthreads();
#pragma unroll
        for (int kk = 0; kk < BK; ++kk) {
            float4 a0 = *(const float4*)&As[kk][ty * 8];
            float4 a1 = *(const float4*)&As[kk][ty * 8 + 4];
            float4 b0 = *(const float4*)&Bs[kk][tx * 8];
            float4 b1 = *(const float4*)&Bs[kk][tx * 8 + 4];
            float a[8] = {a0.x, a0.y, a0.z, a0.w, a1.x, a1.y, a1.z, a1.w};
            float b[8] = {b0.x, b0.y, b0.z, b0.w, b1.x, b1.y, b1.z, b1.w};
#pragma unroll
            for (int i = 0; i < 8; ++i)
#pragma unroll
                for (int j = 0; j < 8; ++j)
                    acc[i][j] = fmaf(a[i], b[j], acc[i][j]);
        }
        __syncthreads();
    }
    float sc[8];
#pragma unroll
    for (int i = 0; i < 8; ++i) sc[i] = 1.0f - ac[i];
#pragma unroll
    for (int i = 0; i < 8; ++i) {
        const int m = m0 + ty * 8 + i;
        const float s = sc[i];
#pragma unroll
        for (int j = 0; j < 8; j += 4) {
            const int n = n0 + tx * 8 + j;
            float4 o;
            o.x = s * (acc[i][j + 0] + bg[n + 0]);
            o.y = s * (acc[i][j + 1] + bg[n + 1]);
            o.z = s * (acc[i][j + 2] + bg[n + 2]);
            o.w = s * (acc[i][j + 3] + bg[n + 3]);
            *(float4*)&out[(size_t)m * VV + n] = o;
        }
    }
}

// ---------------- sparse copy-scatter ----------------
__global__ __launch_bounds__(256)
void scatter_kernel(const float* __restrict__ attn, const float* __restrict__ ac,
                    const int* __restrict__ src, float* __restrict__ out) {
    const int gid = blockIdx.x * 256 + threadIdx.x;  // 131072 total
    const int b = gid >> 14;
    const int rem = gid & 16383;
    const int t = rem >> 7;
    const int s = rem & 127;
    const float a = ac[b];
    const int v = src[s * BB + b];
    atomicAdd(&out[(size_t)(t * BB + b) * VV + v],
              a * attn[(size_t)(b * NTt + t) * NSs + s]);
}

extern "C" void kernel_launch(void* const* d_in, const int* in_sizes, int n_in,
                              void* d_out, int out_size, void* d_ws, size_t ws_size,
                              hipStream_t stream) {
    (void)in_sizes; (void)n_in; (void)out_size;
    const float* htgt = (const float*)d_in[0];
    const float* hsrc = (const float*)d_in[1];
    const int*   src  = (const int*)d_in[2];
    const float* Wq   = (const float*)d_in[3];
    const float* bq   = (const float*)d_in[4];
    const float* Wf   = (const float*)d_in[5];
    const float* bf   = (const float*)d_in[6];
    const float* Wg   = (const float*)d_in[7];
    const float* bg   = (const float*)d_in[8];
    const float* Wc   = (const float*)d_in[9];
    const float* bc   = (const float*)d_in[10];
    float* out = (float*)d_out;

    float* ws   = (float*)d_ws;
    float* QK   = ws;                        // 1,048,576 f
    float* attn = QK + 2048 * 512;           // 131,072 f
    float* wfc  = attn + 131072;             // 512 f
    float* ac   = wfc + 512;                 // 8 f (+ pad)

    size_t fp32_bytes = (size_t)(1048576 + 131072 + 512 + 16) * 4;
    size_t base2 = (fp32_bytes + 255) & ~(size_t)255;
    ushortT* Apack = (ushortT*)((char*)d_ws + base2);               // 8*16*2*4096 ushorts
    ushortT* Bpack = Apack + (size_t)8 * 16 * 2 * LDSC;             // 250*16*2*4096 ushorts
    size_t need = base2 + ((size_t)8 * 16 * 2 * LDSC + (size_t)250 * 16 * 2 * LDSC) * 2;

    const bool use_mfma = (ws_size >= need);
    if (use_mfma) {
        prep_kernel<<<4256, 256, 0, stream>>>(Wg, htgt, Wf, Wc, Bpack, Apack, wfc);
    } else {
        wfc_only_kernel<<<128, 256, 0, stream>>>(Wf, Wc, wfc);
    }
    qkv_gemm<<<dim3(32, 8), 256, 0, stream>>>(htgt, hsrc, Wq, bq, QK);
    attn_kernel<<<512, 256, 0, stream>>>(QK, attn);
    acopy_kernel<<<8, 128, 0, stream>>>(QK, wfc, attn, bf, Wc, bc, ac);

    if (use_mfma) {
        pgen_mfma<<<2000, 256, 0, stream>>>(Apack, Bpack, bg, ac, out);
    } else {
        pgen_gemm<<<dim3(8, 250), 256, 0, stream>>>(htgt, Wg, bg, ac, out);
    }
    scatter_kernel<<<512, 256, 0, stream>>>(attn, ac, src, out);
}